// Round 1
// baseline (1274.583 us; speedup 1.0000x reference)
//
#include <hip/hip_runtime.h>

#define D 128
#define H 256

typedef _Float16 half8 __attribute__((ext_vector_type(8)));
typedef _Float16 half2v __attribute__((ext_vector_type(2)));
typedef float floatx4 __attribute__((ext_vector_type(4)));

// ---------------- CSR build ----------------
__global__ void hist_kernel(const int* __restrict__ dst, int* __restrict__ cnt, int E){
  int e = blockIdx.x*256 + threadIdx.x;
  if (e < E) atomicAdd(&cnt[dst[e]], 1);
}

__global__ void scan_kernel(const int* __restrict__ cnt, int* __restrict__ rowptr, int N){
  __shared__ int sums[1024];
  int tid = threadIdx.x;
  int chunk = (N + 1023) >> 10;
  int beg = tid*chunk, end = min(beg+chunk, N);
  int s = 0;
  for (int i = beg; i < end; ++i) s += cnt[i];
  sums[tid] = s;
  __syncthreads();
  for (int off = 1; off < 1024; off <<= 1){
    int v = 0;
    if (tid >= off) v = sums[tid-off];
    __syncthreads();
    if (tid >= off) sums[tid] += v;
    __syncthreads();
  }
  int run = (tid == 0) ? 0 : sums[tid-1];
  for (int i = beg; i < end; ++i){ rowptr[i] = run; run += cnt[i]; }
  if (tid == 1023) rowptr[N] = sums[1023];
}

__global__ void scatter_kernel(const int* __restrict__ src, const int* __restrict__ dst,
                               const int* __restrict__ ea, const int* __restrict__ rowptr,
                               int* __restrict__ cursor, unsigned* __restrict__ packed, int E){
  int e = blockIdx.x*256 + threadIdx.x;
  if (e >= E) return;
  int d = dst[e];
  int pos = rowptr[d] + atomicAdd(&cursor[d], 1);
  unsigned code = (unsigned)(ea[2*e]*3 + ea[2*e+1]);      // eb,ed in {0,1,2}
  packed[pos] = (code << 20) | (unsigned)src[e];          // src < 2^20
}

// ---------------- input embedding ----------------
__global__ void embed_kernel(const int* __restrict__ x, const float* __restrict__ xemb,
                             _Float16* __restrict__ h, int N){
  int t = blockIdx.x*256 + threadIdx.x;
  if (t >= N*16) return;
  int n = t >> 4, c = (t & 15) * 8;
  int x0 = x[2*n], x1 = x[2*n+1];
  const float* r0 = xemb + (size_t)x0*D + c;
  const float* r1 = xemb + (size_t)(120 + x1)*D + c;
  half8 o;
  #pragma unroll
  for (int j = 0; j < 8; ++j) o[j] = (_Float16)(r0[j] + r1[j]);
  *(half8*)(h + (size_t)n*D + c) = o;
}

// ---------------- per-layer constant tables ----------------
// comb[l][b*3+d] = etab[l][b] + etab[l][6+d]; comb[l][9] = self (bond 4, dir 0)
// sc = gamma*rsqrt(var+eps); sh = (b2-mean)*sc + beta
__global__ void prep_tables(const float* __restrict__ etab, const float* __restrict__ gamma,
                            const float* __restrict__ beta, const float* __restrict__ mean,
                            const float* __restrict__ var, const float* __restrict__ b2,
                            float* __restrict__ comb, float* __restrict__ sc, float* __restrict__ sh){
  int l = blockIdx.x, d = threadIdx.x;
  const float* et = etab + (size_t)l*9*D;
  float* cl = comb + (size_t)l*10*D;
  #pragma unroll
  for (int b = 0; b < 3; ++b)
    #pragma unroll
    for (int dd = 0; dd < 3; ++dd)
      cl[(b*3+dd)*D + d] = et[b*D + d] + et[(6+dd)*D + d];
  cl[9*D + d] = et[4*D + d] + et[6*D + d];
  float A = gamma[l*D+d] * rsqrtf(var[l*D+d] + 1e-5f);
  sc[l*D+d] = A;
  sh[l*D+d] = (b2[l*D+d] - mean[l*D+d]) * A + beta[l*D+d];
}

__global__ void cvt_weights(const float* __restrict__ w1, const float* __restrict__ w2,
                            _Float16* __restrict__ w1h, _Float16* __restrict__ w2h, int n){
  int i = blockIdx.x*256 + threadIdx.x;
  if (i < n){ w1h[i] = (_Float16)w1[i]; w2h[i] = (_Float16)w2[i]; }
}

// ---------------- aggregation: one wave per node ----------------
__global__ __launch_bounds__(256) void agg_kernel(
    const _Float16* __restrict__ h, const unsigned* __restrict__ packed,
    const int* __restrict__ rowptr, const float* __restrict__ comb,
    _Float16* __restrict__ agg, int N){
  __shared__ float cl[10*D];
  int tid = threadIdx.x;
  for (int i = tid; i < 10*D; i += 256) cl[i] = comb[i];
  __syncthreads();
  int node = __builtin_amdgcn_readfirstlane(blockIdx.x*4 + (tid >> 6)); // wave-uniform
  if (node >= N) return;
  int lane = tid & 63;
  int c = lane * 2;
  half2v hv = *(const half2v*)(h + (size_t)node*D + c);
  float2 c9 = *(const float2*)(cl + 9*D + c);
  float ax = (float)hv.x + c9.x;
  float ay = (float)hv.y + c9.y;
  int beg = rowptr[node], end = rowptr[node+1];
  for (int j = beg; j < end; ++j){
    unsigned p = packed[j];
    int s    = (int)(p & 0xFFFFFu);
    int code = (int)(p >> 20);
    half2v v = *(const half2v*)(h + (size_t)s*D + c);
    float2 cc = *(const float2*)(cl + code*D + c);
    ax += (float)v.x + cc.x;
    ay += (float)v.y + cc.y;
  }
  half2v o; o.x = (_Float16)ax; o.y = (_Float16)ay;
  *(half2v*)(agg + (size_t)node*D + c) = o;
}

// ---------------- fused GIN MLP: GEMM1+ReLU -> LDS -> GEMM2+BN ----------------
__global__ __launch_bounds__(256) void mlp_kernel(
    const _Float16* __restrict__ agg, const _Float16* __restrict__ w1h,
    const _Float16* __restrict__ w2h, const float* __restrict__ b1,
    const float* __restrict__ sc, const float* __restrict__ sh,
    _Float16* __restrict__ hout, float* __restrict__ fout,
    int N, int relu_out){
  __shared__ _Float16 hmid[64*264];  // 64 rows x 256 cols, pad->264 (2-way LDS, free)
  int tid = threadIdx.x;
  int wave = tid >> 6, lane = tid & 63;
  int quad = lane >> 4, l15 = lane & 15;
  int r0 = blockIdx.x * 64;

  half8 zf;
  #pragma unroll
  for (int j = 0; j < 8; ++j) zf[j] = (_Float16)0.f;

  // ---- GEMM1: C1[64,256] = A[64,128] x W1^T ; wave w owns cols [64w,64w+64)
  floatx4 acc[4][4] = {};
  #pragma unroll
  for (int ks = 0; ks < 4; ++ks){
    int kk = ks*32 + quad*8;
    half8 af[4], bfr[4];
    #pragma unroll
    for (int mt = 0; mt < 4; ++mt){
      int m = r0 + mt*16 + l15;
      af[mt] = (m < N) ? *(const half8*)(agg + (size_t)m*D + kk) : zf;
    }
    #pragma unroll
    for (int nt = 0; nt < 4; ++nt){
      int n = wave*64 + nt*16 + l15;
      bfr[nt] = *(const half8*)(w1h + (size_t)n*D + kk);   // W1 is [256,128] = B^T layout
    }
    #pragma unroll
    for (int mt = 0; mt < 4; ++mt)
      #pragma unroll
      for (int nt = 0; nt < 4; ++nt)
        acc[mt][nt] = __builtin_amdgcn_mfma_f32_16x16x32_f16(af[mt], bfr[nt], acc[mt][nt], 0, 0, 0);
  }
  // epilogue 1: +b1, ReLU, -> LDS (fp16)
  #pragma unroll
  for (int nt = 0; nt < 4; ++nt){
    int n = wave*64 + nt*16 + l15;
    float bias = b1[n];
    #pragma unroll
    for (int mt = 0; mt < 4; ++mt)
      #pragma unroll
      for (int r = 0; r < 4; ++r){
        int row = mt*16 + quad*4 + r;   // verified C/D layout: col=lane&15, row=quad*4+reg
        hmid[row*264 + n] = (_Float16)fmaxf(acc[mt][nt][r] + bias, 0.f);
      }
  }
  __syncthreads();

  // ---- GEMM2: C2[64,128] = hmid[64,256] x W2^T ; wave w owns cols [32w,32w+32)
  floatx4 acc2[4][2] = {};
  #pragma unroll
  for (int ks = 0; ks < 8; ++ks){
    int kk = ks*32 + quad*8;
    half8 af[4], bg[2];
    #pragma unroll
    for (int mt = 0; mt < 4; ++mt)
      af[mt] = *(const half8*)(hmid + (mt*16 + l15)*264 + kk);
    #pragma unroll
    for (int nt = 0; nt < 2; ++nt){
      int n = wave*32 + nt*16 + l15;
      bg[nt] = *(const half8*)(w2h + (size_t)n*H + kk);    // W2 is [128,256] = B^T layout
    }
    #pragma unroll
    for (int mt = 0; mt < 4; ++mt)
      #pragma unroll
      for (int nt = 0; nt < 2; ++nt)
        acc2[mt][nt] = __builtin_amdgcn_mfma_f32_16x16x32_f16(af[mt], bg[nt], acc2[mt][nt], 0, 0, 0);
  }
  // epilogue 2: BN (folded b2), optional ReLU, store
  #pragma unroll
  for (int nt = 0; nt < 2; ++nt){
    int n = wave*32 + nt*16 + l15;
    float A = sc[n], B = sh[n];
    #pragma unroll
    for (int mt = 0; mt < 4; ++mt)
      #pragma unroll
      for (int r = 0; r < 4; ++r){
        int row = r0 + mt*16 + quad*4 + r;
        if (row < N){
          float v = acc2[mt][nt][r]*A + B;
          if (relu_out) v = fmaxf(v, 0.f);
          if (fout) fout[(size_t)row*D + n] = v;
          else      hout[(size_t)row*D + n] = (_Float16)v;
        }
      }
  }
}

extern "C" void kernel_launch(void* const* d_in, const int* in_sizes, int n_in,
                              void* d_out, int out_size, void* d_ws, size_t ws_size,
                              hipStream_t stream){
  const int*   x     = (const int*)d_in[0];
  const int*   ei    = (const int*)d_in[1];
  const int*   ea    = (const int*)d_in[2];
  const float* xemb  = (const float*)d_in[3];
  const float* etab  = (const float*)d_in[4];
  const float* w1    = (const float*)d_in[5];
  const float* b1    = (const float*)d_in[6];
  const float* w2    = (const float*)d_in[7];
  const float* b2    = (const float*)d_in[8];
  const float* gamma = (const float*)d_in[9];
  const float* beta  = (const float*)d_in[10];
  const float* mean  = (const float*)d_in[11];
  const float* var   = (const float*)d_in[12];
  float* out = (float*)d_out;

  int N = in_sizes[0] / 2;
  int E = in_sizes[1] / 2;

  char* ws = (char*)d_ws;
  size_t off = 0;
  auto alloc = [&](size_t b){ void* p = ws + off; off += (b + 255) & ~(size_t)255; return p; };
  _Float16* h      = (_Float16*)alloc((size_t)N*D*2);
  _Float16* agg    = (_Float16*)alloc((size_t)N*D*2);
  unsigned* packed = (unsigned*)alloc((size_t)E*4);
  int*      rowptr = (int*)alloc((size_t)(N+1)*4);
  int*      cnt    = (int*)alloc((size_t)N*4);
  _Float16* w1h    = (_Float16*)alloc((size_t)5*H*D*2);
  _Float16* w2h    = (_Float16*)alloc((size_t)5*D*H*2);
  float*    comb   = (float*)alloc((size_t)5*10*D*4);
  float*    sc     = (float*)alloc((size_t)5*D*4);
  float*    sh     = (float*)alloc((size_t)5*D*4);

  const int* srcp = ei;
  const int* dstp = ei + E;

  hipMemsetAsync(cnt, 0, (size_t)N*4, stream);
  hist_kernel<<<(E+255)/256, 256, 0, stream>>>(dstp, cnt, E);
  scan_kernel<<<1, 1024, 0, stream>>>(cnt, rowptr, N);
  hipMemsetAsync(cnt, 0, (size_t)N*4, stream);
  scatter_kernel<<<(E+255)/256, 256, 0, stream>>>(srcp, dstp, ea, rowptr, cnt, packed, E);
  cvt_weights<<<(5*H*D+255)/256, 256, 0, stream>>>(w1, w2, w1h, w2h, 5*H*D);
  prep_tables<<<5, 128, 0, stream>>>(etab, gamma, beta, mean, var, b2, comb, sc, sh);
  embed_kernel<<<((size_t)N*16+255)/256, 256, 0, stream>>>(x, xemb, h, N);

  for (int l = 0; l < 5; ++l){
    agg_kernel<<<(N+3)/4, 256, 0, stream>>>(h, packed, rowptr, comb + (size_t)l*10*D, agg, N);
    int last = (l == 4);
    mlp_kernel<<<(N+63)/64, 256, 0, stream>>>(agg, w1h + (size_t)l*H*D, w2h + (size_t)l*D*H,
        b1 + (size_t)l*H, sc + (size_t)l*D, sh + (size_t)l*D,
        last ? (_Float16*)nullptr : h, last ? out : (float*)nullptr,
        N, last ? 0 : 1);
  }
}

// Round 2
// 1114.747 us; speedup vs baseline: 1.1434x; 1.1434x over previous
//
#include <hip/hip_runtime.h>

#define D 128
#define H 256

typedef _Float16 half8 __attribute__((ext_vector_type(8)));
typedef _Float16 half2v __attribute__((ext_vector_type(2)));
typedef float floatx4 __attribute__((ext_vector_type(4)));

// ---------------- CSR build ----------------
__global__ void hist_kernel(const int* __restrict__ dst, int* __restrict__ cnt, int E){
  int e = blockIdx.x*256 + threadIdx.x;
  if (e < E) atomicAdd(&cnt[dst[e]], 1);
}

// ---- multi-block exclusive scan of cnt[N] -> rowptr[N+1] ----
// k1: per-block (1024-elem chunk) total
__global__ __launch_bounds__(256) void scan_part(const int* __restrict__ cnt,
                                                 int* __restrict__ bsum, int N){
  int base = blockIdx.x*1024;
  int tid = threadIdx.x;
  int idx = base + tid*4;
  int4 v = {0,0,0,0};
  if (idx + 3 < N) v = *(const int4*)(cnt + idx);
  else {
    if (idx   < N) v.x = cnt[idx];
    if (idx+1 < N) v.y = cnt[idx+1];
    if (idx+2 < N) v.z = cnt[idx+2];
    if (idx+3 < N) v.w = cnt[idx+3];
  }
  int s = v.x + v.y + v.z + v.w;
  #pragma unroll
  for (int off = 32; off > 0; off >>= 1) s += __shfl_down(s, off, 64);
  __shared__ int ws[4];
  int lane = tid & 63, wave = tid >> 6;
  if (lane == 0) ws[wave] = s;
  __syncthreads();
  if (tid == 0) bsum[blockIdx.x] = ws[0] + ws[1] + ws[2] + ws[3];
}

// k2: single-block Hillis-Steele over nb (<=1024) block sums -> exclusive bases; rowptr[N]=total
__global__ __launch_bounds__(1024) void scan_bsums(const int* __restrict__ bsum,
                                                   int* __restrict__ bbase,
                                                   int* __restrict__ rowptr, int nb, int N){
  __shared__ int sh[1024];
  int tid = threadIdx.x;
  int v = (tid < nb) ? bsum[tid] : 0;
  sh[tid] = v;
  __syncthreads();
  #pragma unroll
  for (int off = 1; off < 1024; off <<= 1){
    int t = 0;
    if (tid >= off) t = sh[tid - off];
    __syncthreads();
    if (tid >= off) sh[tid] += t;
    __syncthreads();
  }
  if (tid < nb) bbase[tid] = sh[tid] - v;   // exclusive base
  if (tid == 0) rowptr[N] = sh[1023];       // grand total
}

// k3: re-read chunk, local exclusive scan + block base -> rowptr[0..N)
__global__ __launch_bounds__(256) void scan_emit(const int* __restrict__ cnt,
                                                 const int* __restrict__ bbase,
                                                 int* __restrict__ rowptr, int N){
  int base = blockIdx.x*1024;
  int tid = threadIdx.x;
  int idx = base + tid*4;
  int4 v = {0,0,0,0};
  if (idx + 3 < N) v = *(const int4*)(cnt + idx);
  else {
    if (idx   < N) v.x = cnt[idx];
    if (idx+1 < N) v.y = cnt[idx+1];
    if (idx+2 < N) v.z = cnt[idx+2];
    if (idx+3 < N) v.w = cnt[idx+3];
  }
  int s = v.x + v.y + v.z + v.w;
  int lane = tid & 63, wave = tid >> 6;
  int incl = s;
  #pragma unroll
  for (int off = 1; off < 64; off <<= 1){
    int t = __shfl_up(incl, off, 64);
    if (lane >= off) incl += t;
  }
  __shared__ int ws[4];
  if (lane == 63) ws[wave] = incl;
  __syncthreads();
  int woff = 0;
  #pragma unroll
  for (int w = 0; w < 4; ++w) if (w < wave) woff += ws[w];
  int off0 = bbase[blockIdx.x] + woff + (incl - s);  // exclusive prefix for element idx
  if (idx   < N) rowptr[idx]   = off0;
  if (idx+1 < N) rowptr[idx+1] = off0 + v.x;
  if (idx+2 < N) rowptr[idx+2] = off0 + v.x + v.y;
  if (idx+3 < N) rowptr[idx+3] = off0 + v.x + v.y + v.z;
}

__global__ void scatter_kernel(const int* __restrict__ src, const int* __restrict__ dst,
                               const int* __restrict__ ea, const int* __restrict__ rowptr,
                               int* __restrict__ cursor, unsigned* __restrict__ packed, int E){
  int e = blockIdx.x*256 + threadIdx.x;
  if (e >= E) return;
  int d = dst[e];
  int pos = rowptr[d] + atomicAdd(&cursor[d], 1);
  unsigned code = (unsigned)(ea[2*e]*3 + ea[2*e+1]);      // eb,ed in {0,1,2}
  packed[pos] = (code << 20) | (unsigned)src[e];          // src < 2^20
}

// ---------------- input embedding ----------------
__global__ void embed_kernel(const int* __restrict__ x, const float* __restrict__ xemb,
                             _Float16* __restrict__ h, int N){
  int t = blockIdx.x*256 + threadIdx.x;
  if (t >= N*16) return;
  int n = t >> 4, c = (t & 15) * 8;
  int x0 = x[2*n], x1 = x[2*n+1];
  const float* r0 = xemb + (size_t)x0*D + c;
  const float* r1 = xemb + (size_t)(120 + x1)*D + c;
  half8 o;
  #pragma unroll
  for (int j = 0; j < 8; ++j) o[j] = (_Float16)(r0[j] + r1[j]);
  *(half8*)(h + (size_t)n*D + c) = o;
}

// ---------------- per-layer constant tables ----------------
__global__ void prep_tables(const float* __restrict__ etab, const float* __restrict__ gamma,
                            const float* __restrict__ beta, const float* __restrict__ mean,
                            const float* __restrict__ var, const float* __restrict__ b2,
                            float* __restrict__ comb, float* __restrict__ sc, float* __restrict__ sh){
  int l = blockIdx.x, d = threadIdx.x;
  const float* et = etab + (size_t)l*9*D;
  float* cl = comb + (size_t)l*10*D;
  #pragma unroll
  for (int b = 0; b < 3; ++b)
    #pragma unroll
    for (int dd = 0; dd < 3; ++dd)
      cl[(b*3+dd)*D + d] = et[b*D + d] + et[(6+dd)*D + d];
  cl[9*D + d] = et[4*D + d] + et[6*D + d];
  float A = gamma[l*D+d] * rsqrtf(var[l*D+d] + 1e-5f);
  sc[l*D+d] = A;
  sh[l*D+d] = (b2[l*D+d] - mean[l*D+d]) * A + beta[l*D+d];
}

__global__ void cvt_weights(const float* __restrict__ w1, const float* __restrict__ w2,
                            _Float16* __restrict__ w1h, _Float16* __restrict__ w2h, int n){
  int i = blockIdx.x*256 + threadIdx.x;
  if (i < n){ w1h[i] = (_Float16)w1[i]; w2h[i] = (_Float16)w2[i]; }
}

// ---------------- aggregation: one wave per node ----------------
__global__ __launch_bounds__(256) void agg_kernel(
    const _Float16* __restrict__ h, const unsigned* __restrict__ packed,
    const int* __restrict__ rowptr, const float* __restrict__ comb,
    _Float16* __restrict__ agg, int N){
  __shared__ float cl[10*D];
  int tid = threadIdx.x;
  for (int i = tid; i < 10*D; i += 256) cl[i] = comb[i];
  __syncthreads();
  int node = __builtin_amdgcn_readfirstlane(blockIdx.x*4 + (tid >> 6)); // wave-uniform
  if (node >= N) return;
  int lane = tid & 63;
  int c = lane * 2;
  half2v hv = *(const half2v*)(h + (size_t)node*D + c);
  float2 c9 = *(const float2*)(cl + 9*D + c);
  float ax = (float)hv.x + c9.x;
  float ay = (float)hv.y + c9.y;
  int beg = rowptr[node], end = rowptr[node+1];
  for (int j = beg; j < end; ++j){
    unsigned p = packed[j];
    int s    = (int)(p & 0xFFFFFu);
    int code = (int)(p >> 20);
    half2v v = *(const half2v*)(h + (size_t)s*D + c);
    float2 cc = *(const float2*)(cl + code*D + c);
    ax += (float)v.x + cc.x;
    ay += (float)v.y + cc.y;
  }
  half2v o; o.x = (_Float16)ax; o.y = (_Float16)ay;
  *(half2v*)(agg + (size_t)node*D + c) = o;
}

// ---------------- fused GIN MLP: GEMM1+ReLU -> LDS -> GEMM2+BN ----------------
__global__ __launch_bounds__(256) void mlp_kernel(
    const _Float16* __restrict__ agg, const _Float16* __restrict__ w1h,
    const _Float16* __restrict__ w2h, const float* __restrict__ b1,
    const float* __restrict__ sc, const float* __restrict__ sh,
    _Float16* __restrict__ hout, float* __restrict__ fout,
    int N, int relu_out){
  __shared__ _Float16 hmid[64*264];  // 64 rows x 256 cols, pad->264 (2-way LDS, free)
  int tid = threadIdx.x;
  int wave = tid >> 6, lane = tid & 63;
  int quad = lane >> 4, l15 = lane & 15;
  int r0 = blockIdx.x * 64;

  half8 zf;
  #pragma unroll
  for (int j = 0; j < 8; ++j) zf[j] = (_Float16)0.f;

  // ---- GEMM1: C1[64,256] = A[64,128] x W1^T ; wave w owns cols [64w,64w+64)
  floatx4 acc[4][4] = {};
  #pragma unroll
  for (int ks = 0; ks < 4; ++ks){
    int kk = ks*32 + quad*8;
    half8 af[4], bfr[4];
    #pragma unroll
    for (int mt = 0; mt < 4; ++mt){
      int m = r0 + mt*16 + l15;
      af[mt] = (m < N) ? *(const half8*)(agg + (size_t)m*D + kk) : zf;
    }
    #pragma unroll
    for (int nt = 0; nt < 4; ++nt){
      int n = wave*64 + nt*16 + l15;
      bfr[nt] = *(const half8*)(w1h + (size_t)n*D + kk);   // W1 is [256,128] = B^T layout
    }
    #pragma unroll
    for (int mt = 0; mt < 4; ++mt)
      #pragma unroll
      for (int nt = 0; nt < 4; ++nt)
        acc[mt][nt] = __builtin_amdgcn_mfma_f32_16x16x32_f16(af[mt], bfr[nt], acc[mt][nt], 0, 0, 0);
  }
  // epilogue 1: +b1, ReLU, -> LDS (fp16)
  #pragma unroll
  for (int nt = 0; nt < 4; ++nt){
    int n = wave*64 + nt*16 + l15;
    float bias = b1[n];
    #pragma unroll
    for (int mt = 0; mt < 4; ++mt)
      #pragma unroll
      for (int r = 0; r < 4; ++r){
        int row = mt*16 + quad*4 + r;   // C/D layout: col=lane&15, row=quad*4+reg
        hmid[row*264 + n] = (_Float16)fmaxf(acc[mt][nt][r] + bias, 0.f);
      }
  }
  __syncthreads();

  // ---- GEMM2: C2[64,128] = hmid[64,256] x W2^T ; wave w owns cols [32w,32w+32)
  floatx4 acc2[4][2] = {};
  #pragma unroll
  for (int ks = 0; ks < 8; ++ks){
    int kk = ks*32 + quad*8;
    half8 af[4], bg[2];
    #pragma unroll
    for (int mt = 0; mt < 4; ++mt)
      af[mt] = *(const half8*)(hmid + (mt*16 + l15)*264 + kk);
    #pragma unroll
    for (int nt = 0; nt < 2; ++nt){
      int n = wave*32 + nt*16 + l15;
      bg[nt] = *(const half8*)(w2h + (size_t)n*H + kk);    // W2 is [128,256] = B^T layout
    }
    #pragma unroll
    for (int mt = 0; mt < 4; ++mt)
      #pragma unroll
      for (int nt = 0; nt < 2; ++nt)
        acc2[mt][nt] = __builtin_amdgcn_mfma_f32_16x16x32_f16(af[mt], bg[nt], acc2[mt][nt], 0, 0, 0);
  }
  // epilogue 2: BN (folded b2), optional ReLU, store
  #pragma unroll
  for (int nt = 0; nt < 2; ++nt){
    int n = wave*32 + nt*16 + l15;
    float A = sc[n], B = sh[n];
    #pragma unroll
    for (int mt = 0; mt < 4; ++mt)
      #pragma unroll
      for (int r = 0; r < 4; ++r){
        int row = r0 + mt*16 + quad*4 + r;
        if (row < N){
          float v = acc2[mt][nt][r]*A + B;
          if (relu_out) v = fmaxf(v, 0.f);
          if (fout) fout[(size_t)row*D + n] = v;
          else      hout[(size_t)row*D + n] = (_Float16)v;
        }
      }
  }
}

extern "C" void kernel_launch(void* const* d_in, const int* in_sizes, int n_in,
                              void* d_out, int out_size, void* d_ws, size_t ws_size,
                              hipStream_t stream){
  const int*   x     = (const int*)d_in[0];
  const int*   ei    = (const int*)d_in[1];
  const int*   ea    = (const int*)d_in[2];
  const float* xemb  = (const float*)d_in[3];
  const float* etab  = (const float*)d_in[4];
  const float* w1    = (const float*)d_in[5];
  const float* b1    = (const float*)d_in[6];
  const float* w2    = (const float*)d_in[7];
  const float* b2    = (const float*)d_in[8];
  const float* gamma = (const float*)d_in[9];
  const float* beta  = (const float*)d_in[10];
  const float* mean  = (const float*)d_in[11];
  const float* var   = (const float*)d_in[12];
  float* out = (float*)d_out;

  int N = in_sizes[0] / 2;
  int E = in_sizes[1] / 2;
  int nb = (N + 1023) / 1024;   // scan blocks (98 for N=100000; must be <= 1024)

  char* ws = (char*)d_ws;
  size_t off = 0;
  auto alloc = [&](size_t b){ void* p = ws + off; off += (b + 255) & ~(size_t)255; return p; };
  _Float16* h      = (_Float16*)alloc((size_t)N*D*2);
  _Float16* agg    = (_Float16*)alloc((size_t)N*D*2);
  unsigned* packed = (unsigned*)alloc((size_t)E*4);
  int*      rowptr = (int*)alloc((size_t)(N+1)*4);
  int*      cnt    = (int*)alloc((size_t)N*4);
  int*      bsum   = (int*)alloc((size_t)nb*4);
  int*      bbase  = (int*)alloc((size_t)nb*4);
  _Float16* w1h    = (_Float16*)alloc((size_t)5*H*D*2);
  _Float16* w2h    = (_Float16*)alloc((size_t)5*D*H*2);
  float*    comb   = (float*)alloc((size_t)5*10*D*4);
  float*    sc     = (float*)alloc((size_t)5*D*4);
  float*    sh     = (float*)alloc((size_t)5*D*4);

  const int* srcp = ei;
  const int* dstp = ei + E;

  hipMemsetAsync(cnt, 0, (size_t)N*4, stream);
  hist_kernel<<<(E+255)/256, 256, 0, stream>>>(dstp, cnt, E);
  scan_part <<<nb, 256, 0, stream>>>(cnt, bsum, N);
  scan_bsums<<<1, 1024, 0, stream>>>(bsum, bbase, rowptr, nb, N);
  scan_emit <<<nb, 256, 0, stream>>>(cnt, bbase, rowptr, N);
  hipMemsetAsync(cnt, 0, (size_t)N*4, stream);
  scatter_kernel<<<(E+255)/256, 256, 0, stream>>>(srcp, dstp, ea, rowptr, cnt, packed, E);
  cvt_weights<<<(5*H*D+255)/256, 256, 0, stream>>>(w1, w2, w1h, w2h, 5*H*D);
  prep_tables<<<5, 128, 0, stream>>>(etab, gamma, beta, mean, var, b2, comb, sc, sh);
  embed_kernel<<<((size_t)N*16+255)/256, 256, 0, stream>>>(x, xemb, h, N);

  for (int l = 0; l < 5; ++l){
    agg_kernel<<<(N+3)/4, 256, 0, stream>>>(h, packed, rowptr, comb + (size_t)l*10*D, agg, N);
    int last = (l == 4);
    mlp_kernel<<<(N+63)/64, 256, 0, stream>>>(agg, w1h + (size_t)l*H*D, w2h + (size_t)l*D*H,
        b1 + (size_t)l*H, sc + (size_t)l*D, sh + (size_t)l*D,
        last ? (_Float16*)nullptr : h, last ? out : (float*)nullptr,
        N, last ? 0 : 1);
  }
}

// Round 3
// 863.400 us; speedup vs baseline: 1.4762x; 1.2911x over previous
//
#include <hip/hip_runtime.h>

#define D 128
#define H 256

typedef _Float16 half8 __attribute__((ext_vector_type(8)));
typedef _Float16 half2v __attribute__((ext_vector_type(2)));
typedef float floatx4 __attribute__((ext_vector_type(4)));

// ---------------- CSR build ----------------
__global__ void hist_kernel(const int* __restrict__ dst, int* __restrict__ cnt, int E){
  int e = blockIdx.x*256 + threadIdx.x;
  if (e < E) atomicAdd(&cnt[dst[e]], 1);
}

__global__ __launch_bounds__(256) void scan_part(const int* __restrict__ cnt,
                                                 int* __restrict__ bsum, int N){
  int base = blockIdx.x*1024;
  int tid = threadIdx.x;
  int idx = base + tid*4;
  int4 v = {0,0,0,0};
  if (idx + 3 < N) v = *(const int4*)(cnt + idx);
  else {
    if (idx   < N) v.x = cnt[idx];
    if (idx+1 < N) v.y = cnt[idx+1];
    if (idx+2 < N) v.z = cnt[idx+2];
    if (idx+3 < N) v.w = cnt[idx+3];
  }
  int s = v.x + v.y + v.z + v.w;
  #pragma unroll
  for (int off = 32; off > 0; off >>= 1) s += __shfl_down(s, off, 64);
  __shared__ int ws[4];
  int lane = tid & 63, wave = tid >> 6;
  if (lane == 0) ws[wave] = s;
  __syncthreads();
  if (tid == 0) bsum[blockIdx.x] = ws[0] + ws[1] + ws[2] + ws[3];
}

__global__ __launch_bounds__(1024) void scan_bsums(const int* __restrict__ bsum,
                                                   int* __restrict__ bbase,
                                                   int* __restrict__ rowptr, int nb, int N){
  __shared__ int sh[1024];
  int tid = threadIdx.x;
  int v = (tid < nb) ? bsum[tid] : 0;
  sh[tid] = v;
  __syncthreads();
  #pragma unroll
  for (int off = 1; off < 1024; off <<= 1){
    int t = 0;
    if (tid >= off) t = sh[tid - off];
    __syncthreads();
    if (tid >= off) sh[tid] += t;
    __syncthreads();
  }
  if (tid < nb) bbase[tid] = sh[tid] - v;
  if (tid == 0) rowptr[N] = sh[1023];
}

__global__ __launch_bounds__(256) void scan_emit(const int* __restrict__ cnt,
                                                 const int* __restrict__ bbase,
                                                 int* __restrict__ rowptr, int N){
  int base = blockIdx.x*1024;
  int tid = threadIdx.x;
  int idx = base + tid*4;
  int4 v = {0,0,0,0};
  if (idx + 3 < N) v = *(const int4*)(cnt + idx);
  else {
    if (idx   < N) v.x = cnt[idx];
    if (idx+1 < N) v.y = cnt[idx+1];
    if (idx+2 < N) v.z = cnt[idx+2];
    if (idx+3 < N) v.w = cnt[idx+3];
  }
  int s = v.x + v.y + v.z + v.w;
  int lane = tid & 63, wave = tid >> 6;
  int incl = s;
  #pragma unroll
  for (int off = 1; off < 64; off <<= 1){
    int t = __shfl_up(incl, off, 64);
    if (lane >= off) incl += t;
  }
  __shared__ int ws[4];
  if (lane == 63) ws[wave] = incl;
  __syncthreads();
  int woff = 0;
  #pragma unroll
  for (int w = 0; w < 4; ++w) if (w < wave) woff += ws[w];
  int off0 = bbase[blockIdx.x] + woff + (incl - s);
  if (idx   < N) rowptr[idx]   = off0;
  if (idx+1 < N) rowptr[idx+1] = off0 + v.x;
  if (idx+2 < N) rowptr[idx+2] = off0 + v.x + v.y;
  if (idx+3 < N) rowptr[idx+3] = off0 + v.x + v.y + v.z;
}

__global__ void scatter_kernel(const int* __restrict__ src, const int* __restrict__ dst,
                               const int* __restrict__ ea, const int* __restrict__ rowptr,
                               int* __restrict__ cursor, unsigned* __restrict__ packed, int E){
  int e = blockIdx.x*256 + threadIdx.x;
  if (e >= E) return;
  int d = dst[e];
  int pos = rowptr[d] + atomicAdd(&cursor[d], 1);
  unsigned code = (unsigned)(ea[2*e]*3 + ea[2*e+1]);
  packed[pos] = (code << 20) | (unsigned)src[e];
}

// ---------------- input embedding ----------------
__global__ void embed_kernel(const int* __restrict__ x, const float* __restrict__ xemb,
                             _Float16* __restrict__ h, int N){
  int t = blockIdx.x*256 + threadIdx.x;
  if (t >= N*16) return;
  int n = t >> 4, c = (t & 15) * 8;
  int x0 = x[2*n], x1 = x[2*n+1];
  const float* r0 = xemb + (size_t)x0*D + c;
  const float* r1 = xemb + (size_t)(120 + x1)*D + c;
  half8 o;
  #pragma unroll
  for (int j = 0; j < 8; ++j) o[j] = (_Float16)(r0[j] + r1[j]);
  *(half8*)(h + (size_t)n*D + c) = o;
}

// ---------------- per-layer constant tables ----------------
__global__ void prep_tables(const float* __restrict__ etab, const float* __restrict__ gamma,
                            const float* __restrict__ beta, const float* __restrict__ mean,
                            const float* __restrict__ var, const float* __restrict__ b2,
                            float* __restrict__ comb, float* __restrict__ sc, float* __restrict__ sh){
  int l = blockIdx.x, d = threadIdx.x;
  const float* et = etab + (size_t)l*9*D;
  float* cl = comb + (size_t)l*10*D;
  #pragma unroll
  for (int b = 0; b < 3; ++b)
    #pragma unroll
    for (int dd = 0; dd < 3; ++dd)
      cl[(b*3+dd)*D + d] = et[b*D + d] + et[(6+dd)*D + d];
  cl[9*D + d] = et[4*D + d] + et[6*D + d];
  float A = gamma[l*D+d] * rsqrtf(var[l*D+d] + 1e-5f);
  sc[l*D+d] = A;
  sh[l*D+d] = (b2[l*D+d] - mean[l*D+d]) * A + beta[l*D+d];
}

__global__ void cvt_weights(const float* __restrict__ w1, const float* __restrict__ w2,
                            _Float16* __restrict__ w1h, _Float16* __restrict__ w2h, int n){
  int i = blockIdx.x*256 + threadIdx.x;
  if (i < n){ w1h[i] = (_Float16)w1[i]; w2h[i] = (_Float16)w2[i]; }
}

// ---------------- aggregation: one wave per node, 8 gathers in flight ----------------
__global__ __launch_bounds__(256) void agg_kernel(
    const _Float16* __restrict__ h, const unsigned* __restrict__ packed,
    const int* __restrict__ rowptr, const float* __restrict__ comb,
    _Float16* __restrict__ agg, int N){
  __shared__ float cl[10*D];
  int tid = threadIdx.x;
  for (int i = tid; i < 10*D; i += 256) cl[i] = comb[i];
  __syncthreads();
  int node = __builtin_amdgcn_readfirstlane(blockIdx.x*4 + (tid >> 6)); // wave-uniform
  if (node >= N) return;
  int lane = tid & 63;
  int c = lane * 2;
  half2v hv = *(const half2v*)(h + (size_t)node*D + c);
  float2 c9 = *(const float2*)(cl + 9*D + c);
  float ax = (float)hv.x + c9.x;
  float ay = (float)hv.y + c9.y;
  int beg = rowptr[node], end = rowptr[node+1];
  // unroll-8 with wave-uniform predication: 8 packed loads then 8 gathers in flight
  for (int j = beg; j < end; j += 8){
    int m = end - j;                         // wave-uniform remaining
    unsigned p[8];
    #pragma unroll
    for (int k = 0; k < 8; ++k) if (k < m) p[k] = packed[j+k];
    half2v v[8]; float2 cc[8];
    #pragma unroll
    for (int k = 0; k < 8; ++k) if (k < m){
      int s    = (int)(p[k] & 0xFFFFFu);
      v[k]  = *(const half2v*)(h + (size_t)s*D + c);
      cc[k] = *(const float2*)(cl + (int)(p[k] >> 20)*D + c);
    }
    #pragma unroll
    for (int k = 0; k < 8; ++k) if (k < m){
      ax += (float)v[k].x + cc[k].x;
      ay += (float)v[k].y + cc[k].y;
    }
  }
  half2v o; o.x = (_Float16)ax; o.y = (_Float16)ay;
  *(half2v*)(agg + (size_t)node*D + c) = o;
}

// ---------------- fused GIN MLP: stage A->LDS, GEMM1+ReLU -> LDS -> GEMM2+BN ----------------
// LDS aliased: atile (64x136 halfs, 17.4 KB) lives only until GEMM1 done,
// then the same block is reused as hmid (64x264 halfs, 33.8 KB) -> 4 blocks/CU.
__global__ __launch_bounds__(256) void mlp_kernel(
    const _Float16* __restrict__ agg, const _Float16* __restrict__ w1h,
    const _Float16* __restrict__ w2h, const float* __restrict__ b1,
    const float* __restrict__ sc, const float* __restrict__ sh,
    _Float16* __restrict__ hout, float* __restrict__ fout,
    int N, int relu_out){
  __shared__ __align__(16) char smem[64*264*2];
  _Float16* atile = (_Float16*)smem;   // stride 136 (272 B: bank stride 4 -> 2-way, free)
  _Float16* hmid  = (_Float16*)smem;   // stride 264 (528 B)
  int tid = threadIdx.x;
  int wave = tid >> 6, lane = tid & 63;
  int quad = lane >> 4, l15 = lane & 15;
  int r0 = blockIdx.x * 64;

  half8 zf;
  #pragma unroll
  for (int j = 0; j < 8; ++j) zf[j] = (_Float16)0.f;

  // ---- stage A tile [64x128] fp16 -> LDS (coalesced 16 B/lane)
  #pragma unroll
  for (int i = 0; i < 4; ++i){
    int ci = i*256 + tid;            // 0..1023 16B-chunks
    int row = ci >> 4, col = (ci & 15) * 8;
    int m = r0 + row;
    half8 v = (m < N) ? *(const half8*)(agg + (size_t)m*D + col) : zf;
    *(half8*)(atile + row*136 + col) = v;
  }
  __syncthreads();

  // ---- GEMM1: C1[64,256] = A x W1^T ; wave w owns cols [64w,64w+64); B prefetch 1 ks ahead
  floatx4 acc[4][4] = {};
  half8 bcur[4], bnxt[4];
  #pragma unroll
  for (int nt = 0; nt < 4; ++nt)
    bcur[nt] = *(const half8*)(w1h + (size_t)(wave*64 + nt*16 + l15)*D + quad*8);
  #pragma unroll
  for (int ks = 0; ks < 4; ++ks){
    int kk = ks*32 + quad*8;
    if (ks < 3){
      #pragma unroll
      for (int nt = 0; nt < 4; ++nt)
        bnxt[nt] = *(const half8*)(w1h + (size_t)(wave*64 + nt*16 + l15)*D + kk + 32);
    }
    half8 af[4];
    #pragma unroll
    for (int mt = 0; mt < 4; ++mt)
      af[mt] = *(const half8*)(atile + (mt*16 + l15)*136 + kk);
    #pragma unroll
    for (int mt = 0; mt < 4; ++mt)
      #pragma unroll
      for (int nt = 0; nt < 4; ++nt)
        acc[mt][nt] = __builtin_amdgcn_mfma_f32_16x16x32_f16(af[mt], bcur[nt], acc[mt][nt], 0, 0, 0);
    #pragma unroll
    for (int nt = 0; nt < 4; ++nt) bcur[nt] = bnxt[nt];
  }
  __syncthreads();   // all waves done reading atile before hmid overwrites it

  // epilogue 1: +b1, ReLU, -> LDS (fp16)
  #pragma unroll
  for (int nt = 0; nt < 4; ++nt){
    int n = wave*64 + nt*16 + l15;
    float bias = b1[n];
    #pragma unroll
    for (int mt = 0; mt < 4; ++mt)
      #pragma unroll
      for (int r = 0; r < 4; ++r){
        int row = mt*16 + quad*4 + r;   // C/D layout: col=lane&15, row=quad*4+reg
        hmid[row*264 + n] = (_Float16)fmaxf(acc[mt][nt][r] + bias, 0.f);
      }
  }
  __syncthreads();

  // ---- GEMM2: C2[64,128] = hmid x W2^T ; wave w owns cols [32w,32w+32); B prefetch 1 ahead
  floatx4 acc2[4][2] = {};
  half8 gcur[2], gnxt[2];
  #pragma unroll
  for (int nt = 0; nt < 2; ++nt)
    gcur[nt] = *(const half8*)(w2h + (size_t)(wave*32 + nt*16 + l15)*H + quad*8);
  #pragma unroll
  for (int ks = 0; ks < 8; ++ks){
    int kk = ks*32 + quad*8;
    if (ks < 7){
      #pragma unroll
      for (int nt = 0; nt < 2; ++nt)
        gnxt[nt] = *(const half8*)(w2h + (size_t)(wave*32 + nt*16 + l15)*H + kk + 32);
    }
    half8 af[4];
    #pragma unroll
    for (int mt = 0; mt < 4; ++mt)
      af[mt] = *(const half8*)(hmid + (mt*16 + l15)*264 + kk);
    #pragma unroll
    for (int mt = 0; mt < 4; ++mt)
      #pragma unroll
      for (int nt = 0; nt < 2; ++nt)
        acc2[mt][nt] = __builtin_amdgcn_mfma_f32_16x16x32_f16(af[mt], gcur[nt], acc2[mt][nt], 0, 0, 0);
    #pragma unroll
    for (int nt = 0; nt < 2; ++nt) gcur[nt] = gnxt[nt];
  }

  // epilogue 2: BN (folded b2), optional ReLU, store
  #pragma unroll
  for (int nt = 0; nt < 2; ++nt){
    int n = wave*32 + nt*16 + l15;
    float A = sc[n], B = sh[n];
    #pragma unroll
    for (int mt = 0; mt < 4; ++mt)
      #pragma unroll
      for (int r = 0; r < 4; ++r){
        int row = r0 + mt*16 + quad*4 + r;
        if (row < N){
          float v = acc2[mt][nt][r]*A + B;
          if (relu_out) v = fmaxf(v, 0.f);
          if (fout) fout[(size_t)row*D + n] = v;
          else      hout[(size_t)row*D + n] = (_Float16)v;
        }
      }
  }
}

extern "C" void kernel_launch(void* const* d_in, const int* in_sizes, int n_in,
                              void* d_out, int out_size, void* d_ws, size_t ws_size,
                              hipStream_t stream){
  const int*   x     = (const int*)d_in[0];
  const int*   ei    = (const int*)d_in[1];
  const int*   ea    = (const int*)d_in[2];
  const float* xemb  = (const float*)d_in[3];
  const float* etab  = (const float*)d_in[4];
  const float* w1    = (const float*)d_in[5];
  const float* b1    = (const float*)d_in[6];
  const float* w2    = (const float*)d_in[7];
  const float* b2    = (const float*)d_in[8];
  const float* gamma = (const float*)d_in[9];
  const float* beta  = (const float*)d_in[10];
  const float* mean  = (const float*)d_in[11];
  const float* var   = (const float*)d_in[12];
  float* out = (float*)d_out;

  int N = in_sizes[0] / 2;
  int E = in_sizes[1] / 2;
  int nb = (N + 1023) / 1024;

  char* ws = (char*)d_ws;
  size_t off = 0;
  auto alloc = [&](size_t b){ void* p = ws + off; off += (b + 255) & ~(size_t)255; return p; };
  _Float16* h      = (_Float16*)alloc((size_t)N*D*2);
  _Float16* agg    = (_Float16*)alloc((size_t)N*D*2);
  unsigned* packed = (unsigned*)alloc((size_t)E*4);
  int*      rowptr = (int*)alloc((size_t)(N+1)*4);
  int*      cnt    = (int*)alloc((size_t)N*4);
  int*      bsum   = (int*)alloc((size_t)nb*4);
  int*      bbase  = (int*)alloc((size_t)nb*4);
  _Float16* w1h    = (_Float16*)alloc((size_t)5*H*D*2);
  _Float16* w2h    = (_Float16*)alloc((size_t)5*D*H*2);
  float*    comb   = (float*)alloc((size_t)5*10*D*4);
  float*    sc     = (float*)alloc((size_t)5*D*4);
  float*    sh     = (float*)alloc((size_t)5*D*4);

  const int* srcp = ei;
  const int* dstp = ei + E;

  hipMemsetAsync(cnt, 0, (size_t)N*4, stream);
  hist_kernel<<<(E+255)/256, 256, 0, stream>>>(dstp, cnt, E);
  scan_part <<<nb, 256, 0, stream>>>(cnt, bsum, N);
  scan_bsums<<<1, 1024, 0, stream>>>(bsum, bbase, rowptr, nb, N);
  scan_emit <<<nb, 256, 0, stream>>>(cnt, bbase, rowptr, N);
  hipMemsetAsync(cnt, 0, (size_t)N*4, stream);
  scatter_kernel<<<(E+255)/256, 256, 0, stream>>>(srcp, dstp, ea, rowptr, cnt, packed, E);
  cvt_weights<<<(5*H*D+255)/256, 256, 0, stream>>>(w1, w2, w1h, w2h, 5*H*D);
  prep_tables<<<5, 128, 0, stream>>>(etab, gamma, beta, mean, var, b2, comb, sc, sh);
  embed_kernel<<<((size_t)N*16+255)/256, 256, 0, stream>>>(x, xemb, h, N);

  for (int l = 0; l < 5; ++l){
    agg_kernel<<<(N+3)/4, 256, 0, stream>>>(h, packed, rowptr, comb + (size_t)l*10*D, agg, N);
    int last = (l == 4);
    mlp_kernel<<<(N+63)/64, 256, 0, stream>>>(agg, w1h + (size_t)l*H*D, w2h + (size_t)l*D*H,
        b1 + (size_t)l*H, sc + (size_t)l*D, sh + (size_t)l*D,
        last ? (_Float16*)nullptr : h, last ? out : (float*)nullptr,
        N, last ? 0 : 1);
  }
}